// Round 1
// baseline (1457.342 us; speedup 1.0000x reference)
//
#include <hip/hip_runtime.h>
#include <math.h>

#define T 1024
#define C 192
#define FCH 8
#define LN_EPS 1e-5f

__device__ __forceinline__ float silu_f(float x){ return x / (1.0f + __expf(-x)); }

// ---------------- kernel 0: inclusive scan of durations ----------------
__global__ void k_scan(const int* __restrict__ d, float* __restrict__ Sd, float* __restrict__ Ed){
    __shared__ int s[T];
    int tid = threadIdx.x;
    int v = d[tid];
    s[tid] = v;
    for(int off=1; off<T; off<<=1){
        __syncthreads();
        int add = (tid>=off) ? s[tid-off] : 0;
        __syncthreads();
        s[tid] += add;
    }
    __syncthreads();
    Ed[tid] = (float)s[tid];
    Sd[tid] = (float)(s[tid]-v);
}

// ---------------- kernel 1: x = silu(H^T W_in + b_in) [T][C] ----------------
__global__ void k_proj_in(const float* __restrict__ H, const float* __restrict__ W_in,
                          const float* __restrict__ b_in, float* __restrict__ x){
    int t = blockIdx.x;
    int c = threadIdx.x;           // 192 threads
    float acc = b_in[c];
    for(int ci=0; ci<C; ci++){
        acc += H[ci*T + t] * W_in[ci*C + c];
    }
    x[t*C + c] = silu_f(acc);
}

// ---------------- kernel 2: conv1d(C->8,k3,p1) + LN(8) + SiLU -> xf [T][8] ----------------
__global__ void k_conv_ln(const float* __restrict__ x, const float* __restrict__ conv_w,
                          const float* __restrict__ conv_b, const float* __restrict__ gamma,
                          const float* __restrict__ beta, float* __restrict__ xf){
    __shared__ float xc[32][FCH];
    int tid = threadIdx.x;          // 256 = 32 t x 8 f
    int tl = tid >> 3, f = tid & 7;
    int t = blockIdx.x*32 + tl;
    float acc = conv_b[f];
    for(int k=0;k<3;k++){
        int tt = t + k - 1;
        if(tt>=0 && tt<T){
            const float* xr = x + tt*C;
            const float* wr = conv_w + f*C*3 + k;   // conv_w[f][c][k]
            for(int c2=0;c2<C;c2++) acc += xr[c2]*wr[c2*3];
        }
    }
    xc[tl][f] = acc;
    __syncthreads();
    float mu=0.f;
    #pragma unroll
    for(int j=0;j<FCH;j++) mu += xc[tl][j];
    mu *= (1.0f/FCH);
    float var=0.f;
    #pragma unroll
    for(int j=0;j<FCH;j++){ float dd = xc[tl][j]-mu; var += dd*dd; }
    var *= (1.0f/FCH);
    float vi = rsqrtf(var + LN_EPS);
    float v = (acc - mu)*vi*gamma[f] + beta[f];
    xf[t*FCH+f] = silu_f(v);
}

// ---------------- kernel 3: per-frame fused MLP + softmax + WH/WC + epilogue ----------------
// block = 256 threads, one block per mel frame m
__global__ void __launch_bounds__(256)
k_main(const float* __restrict__ H, const float* __restrict__ Sd,
       const float* __restrict__ Ed, const float* __restrict__ xf,
       const float* __restrict__ wp1, const float* __restrict__ bp1,
       const float* __restrict__ wp2, const float* __restrict__ bp2,
       const float* __restrict__ wc1, const float* __restrict__ bc1,
       const float* __restrict__ wc2, const float* __restrict__ bc2,
       const float* __restrict__ W_WH, const float* __restrict__ b_WH,
       const float* __restrict__ W_WC, const float* __restrict__ b_WC,
       const float* __restrict__ W_out, const float* __restrict__ b_out,
       float* __restrict__ out, int M)
{
    __shared__ float w_l[T][4];      // logits -> exp -> normalized weights
    __shared__ float cm_l[T][2];     // content values
    __shared__ float Hc[32*193];     // H chunk, transposed, padded stride 193
    __shared__ float red[1024];      // reductions
    __shared__ float wsm[286];       // small MLP weights
    __shared__ float WH_l[768];
    __shared__ float WC_l[8];
    __shared__ float O_l[192];

    int m   = blockIdx.x;
    int tid = threadIdx.x;

    // stage tiny weights into LDS
    for(int i=tid;i<100;i+=256) wsm[i]      = wp1[i];
    for(int i=tid;i<10; i+=256) wsm[100+i]  = bp1[i];
    for(int i=tid;i<40; i+=256) wsm[110+i]  = wp2[i];
    for(int i=tid;i<4;  i+=256) wsm[150+i]  = bp2[i];
    for(int i=tid;i<100;i+=256) wsm[154+i]  = wc1[i];
    for(int i=tid;i<10; i+=256) wsm[254+i]  = bc1[i];
    for(int i=tid;i<20; i+=256) wsm[264+i]  = wc2[i];
    for(int i=tid;i<2;  i+=256) wsm[284+i]  = bc2[i];
    __syncthreads();

    // ---- phase 1: per-t tiny MLPs -> logits + content ----
    float fi = (float)(m+1);
    float pmax[4] = {-1e30f,-1e30f,-1e30f,-1e30f};
    for(int t=tid; t<T; t+=256){
        float fv[10];
        fv[0] = fi - Sd[t];
        fv[1] = Ed[t] - fi;
        #pragma unroll
        for(int j=0;j<8;j++) fv[2+j] = xf[t*8+j];
        float h1[10];
        #pragma unroll
        for(int j=0;j<10;j++){
            float a = wsm[100+j];
            #pragma unroll
            for(int i=0;i<10;i++) a += fv[i]*wsm[i*10+j];
            h1[j] = silu_f(a);
        }
        #pragma unroll
        for(int q=0;q<4;q++){
            float a = wsm[150+q];
            #pragma unroll
            for(int j=0;j<10;j++) a += h1[j]*wsm[110 + j*4 + q];
            w_l[t][q] = a;
            pmax[q] = fmaxf(pmax[q], a);
        }
        float g1[10];
        #pragma unroll
        for(int j=0;j<10;j++){
            float a = wsm[254+j];
            #pragma unroll
            for(int i=0;i<10;i++) a += fv[i]*wsm[154 + i*10 + j];
            g1[j] = silu_f(a);
        }
        #pragma unroll
        for(int p=0;p<2;p++){
            float a = wsm[284+p];
            #pragma unroll
            for(int j=0;j<10;j++) a += g1[j]*wsm[264 + j*2 + p];
            cm_l[t][p] = silu_f(a);
        }
    }

    // ---- softmax over t per q: max ----
    #pragma unroll
    for(int q=0;q<4;q++) red[tid*4+q] = pmax[q];
    __syncthreads();
    for(int s=128;s>0;s>>=1){
        if(tid<s){
            #pragma unroll
            for(int q=0;q<4;q++) red[tid*4+q] = fmaxf(red[tid*4+q], red[(tid+s)*4+q]);
        }
        __syncthreads();
    }
    float mx[4];
    #pragma unroll
    for(int q=0;q<4;q++) mx[q]=red[q];
    __syncthreads();

    // ---- exp + sum ----
    float psum[4]={0.f,0.f,0.f,0.f};
    for(int t=tid;t<T;t+=256){
        #pragma unroll
        for(int q=0;q<4;q++){
            float e = __expf(w_l[t][q]-mx[q]);
            w_l[t][q] = e;
            psum[q] += e;
        }
    }
    #pragma unroll
    for(int q=0;q<4;q++) red[tid*4+q]=psum[q];
    __syncthreads();
    for(int s=128;s>0;s>>=1){
        if(tid<s){
            #pragma unroll
            for(int q=0;q<4;q++) red[tid*4+q] += red[(tid+s)*4+q];
        }
        __syncthreads();
    }
    float inv[4];
    #pragma unroll
    for(int q=0;q<4;q++) inv[q] = 1.0f/red[q];
    __syncthreads();

    // ---- normalize weights in place ----
    for(int t=tid;t<T;t+=256){
        #pragma unroll
        for(int q=0;q<4;q++) w_l[t][q]*=inv[q];
    }
    __syncthreads();

    // ---- WC[q][p] = sum_t w*cm ----
    {
        int o = tid & 7; int q = o>>1, p = o&1;
        float s2=0.f;
        for(int t=(tid>>3); t<T; t+=32) s2 += w_l[t][q]*cm_l[t][p];
        red[tid]=s2;
        __syncthreads();
        for(int s=128;s>=8;s>>=1){
            if(tid<s) red[tid]+=red[tid+s];
            __syncthreads();
        }
        if(tid<8) WC_l[tid]=red[tid];
    }

    // ---- pass 2: WH[q][h] = sum_t w[t][q]*H[h][t], H staged in LDS ----
    int q4 = tid>>6, lane = tid&63;     // wave q4 handles q=q4; lane -> 3 h values
    float acc0=0.f, acc1=0.f, acc2=0.f;
    for(int tc=0; tc<T; tc+=32){
        __syncthreads();   // previous chunk consumed (also closes WC reduce)
        {
            int tl = tid & 31, h0 = tid >> 5;  // 8 rows per pass
            for(int hh=h0; hh<C; hh+=8)
                Hc[tl*193+hh] = H[hh*T + tc + tl];
        }
        __syncthreads();
        #pragma unroll
        for(int tl=0; tl<32; tl++){
            float wv = w_l[tc+tl][q4];
            int base = tl*193 + lane*3;
            acc0 += wv*Hc[base];
            acc1 += wv*Hc[base+1];
            acc2 += wv*Hc[base+2];
        }
    }
    WH_l[q4*192 + lane*3    ] = acc0;
    WH_l[q4*192 + lane*3 + 1] = acc1;
    WH_l[q4*192 + lane*3 + 2] = acc2;
    __syncthreads();

    // ---- epilogue: O = (WH@W_WH + WC@W_WC + b) @ W_out + b_out ----
    if(tid<C){
        int c2 = tid;
        float o1 = b_WH[c2] + b_WC[c2];
        for(int i=0;i<768;i++) o1 += WH_l[i]*W_WH[i*C+c2];
        #pragma unroll
        for(int i=0;i<8;i++)  o1 += WC_l[i]*W_WC[i*C+c2];
        O_l[c2] = o1;
    }
    __syncthreads();
    if(tid<C){
        int c2 = tid;
        float o2 = b_out[c2];
        for(int i=0;i<C;i++) o2 += O_l[i]*W_out[i*C+c2];
        out[c2*M + m] = o2;      // O transposed [C, M]
    }
    if(tid==C) out[C*M + m] = 0.0f;   // ~frame_valid == False -> 0
}

// ---------------- host ----------------
extern "C" void kernel_launch(void* const* d_in, const int* in_sizes, int n_in,
                              void* d_out, int out_size, void* d_ws, size_t ws_size,
                              hipStream_t stream)
{
    const float* H      = (const float*)d_in[0];
    const int*   d      = (const int*)  d_in[1];
    // d_in[2] = src_mask (all True) -- unused
    const float* W_in   = (const float*)d_in[3];
    const float* b_in   = (const float*)d_in[4];
    const float* conv_w = (const float*)d_in[5];
    const float* conv_b = (const float*)d_in[6];
    const float* gamma  = (const float*)d_in[7];
    const float* beta   = (const float*)d_in[8];
    const float* wp1    = (const float*)d_in[9];
    const float* bp1    = (const float*)d_in[10];
    const float* wp2    = (const float*)d_in[11];
    const float* bp2    = (const float*)d_in[12];
    const float* wc1    = (const float*)d_in[13];
    const float* bc1    = (const float*)d_in[14];
    const float* wc2    = (const float*)d_in[15];
    const float* bc2    = (const float*)d_in[16];
    const float* W_WH   = (const float*)d_in[17];
    const float* b_WH   = (const float*)d_in[18];
    const float* W_WC   = (const float*)d_in[19];
    const float* b_WC   = (const float*)d_in[20];
    const float* W_out  = (const float*)d_in[21];
    const float* b_out  = (const float*)d_in[22];

    float* out = (float*)d_out;
    int M = out_size / 193;          // out = [192*M] O  + [M] ~frame_valid

    float* ws = (float*)d_ws;
    float* Sd = ws;                  // 1024
    float* Ed = ws + 1024;           // 1024
    float* x  = ws + 2048;           // 1024*192
    float* xf = ws + 2048 + T*C;     // 1024*8

    hipLaunchKernelGGL(k_scan,    dim3(1),    dim3(1024), 0, stream, d, Sd, Ed);
    hipLaunchKernelGGL(k_proj_in, dim3(T),    dim3(C),    0, stream, H, W_in, b_in, x);
    hipLaunchKernelGGL(k_conv_ln, dim3(T/32), dim3(256),  0, stream, x, conv_w, conv_b, gamma, beta, xf);
    hipLaunchKernelGGL(k_main,    dim3(M),    dim3(256),  0, stream,
                       H, Sd, Ed, xf,
                       wp1, bp1, wp2, bp2, wc1, bc1, wc2, bc2,
                       W_WH, b_WH, W_WC, b_WC, W_out, b_out,
                       out, M);
}

// Round 2
// 567.941 us; speedup vs baseline: 2.5660x; 2.5660x over previous
//
#include <hip/hip_runtime.h>
#include <math.h>

#define T 1024
#define C 192
#define FCH 8
#define LN_EPS 1e-5f

__device__ __forceinline__ float silu_f(float x){ return x / (1.0f + __expf(-x)); }
__device__ __forceinline__ float wred_max(float v){
    #pragma unroll
    for(int o=32;o;o>>=1) v = fmaxf(v, __shfl_xor(v,o));
    return v;
}
__device__ __forceinline__ float wred_sum(float v){
    #pragma unroll
    for(int o=32;o;o>>=1) v += __shfl_xor(v,o);
    return v;
}

// ---------------- kernel 0: inclusive scan of durations ----------------
__global__ void k_scan(const int* __restrict__ d, float* __restrict__ Sd, float* __restrict__ Ed){
    __shared__ int s[T];
    int tid = threadIdx.x;
    int v = d[tid];
    s[tid] = v;
    for(int off=1; off<T; off<<=1){
        __syncthreads();
        int add = (tid>=off) ? s[tid-off] : 0;
        __syncthreads();
        s[tid] += add;
    }
    __syncthreads();
    Ed[tid] = (float)s[tid];
    Sd[tid] = (float)(s[tid]-v);
}

// ---------------- kernel 1: x = silu(H^T W_in + b_in) [T][C] ----------------
__global__ void k_proj_in(const float* __restrict__ H, const float* __restrict__ W_in,
                          const float* __restrict__ b_in, float* __restrict__ x){
    int t = blockIdx.x;
    int c = threadIdx.x;           // 192 threads
    float acc = b_in[c];
    for(int ci=0; ci<C; ci++){
        acc += H[ci*T + t] * W_in[ci*C + c];
    }
    x[t*C + c] = silu_f(acc);
}

// ---------------- kernel 2: conv1d(C->8,k3,p1) + LN(8) + SiLU -> xf [T][8] ----------------
__global__ void k_conv_ln(const float* __restrict__ x, const float* __restrict__ conv_w,
                          const float* __restrict__ conv_b, const float* __restrict__ gamma,
                          const float* __restrict__ beta, float* __restrict__ xf){
    __shared__ float xc[32][FCH];
    int tid = threadIdx.x;          // 256 = 32 t x 8 f
    int tl = tid >> 3, f = tid & 7;
    int t = blockIdx.x*32 + tl;
    float acc = conv_b[f];
    for(int k=0;k<3;k++){
        int tt = t + k - 1;
        if(tt>=0 && tt<T){
            const float* xr = x + tt*C;
            const float* wr = conv_w + f*C*3 + k;   // conv_w[f][c][k]
            for(int c2=0;c2<C;c2++) acc += xr[c2]*wr[c2*3];
        }
    }
    xc[tl][f] = acc;
    __syncthreads();
    float mu=0.f;
    #pragma unroll
    for(int j=0;j<FCH;j++) mu += xc[tl][j];
    mu *= (1.0f/FCH);
    float var=0.f;
    #pragma unroll
    for(int j=0;j<FCH;j++){ float dd = xc[tl][j]-mu; var += dd*dd; }
    var *= (1.0f/FCH);
    float vi = rsqrtf(var + LN_EPS);
    float v = (acc - mu)*vi*gamma[f] + beta[f];
    xf[t*FCH+f] = silu_f(v);
}

// ---------------- kernel 3: A[t][20] = m-independent first-layer preacts; uv ----------------
__global__ void k_A(const float* __restrict__ Sd, const float* __restrict__ Ed,
                    const float* __restrict__ xf,
                    const float* __restrict__ wp1, const float* __restrict__ bp1,
                    const float* __restrict__ wc1, const float* __restrict__ bc1,
                    float* __restrict__ A, float* __restrict__ uv){
    int b = blockIdx.x, tid = threadIdx.x;
    if(b==4){
        if(tid<10){
            uv[tid]    = wp1[tid] - wp1[10+tid];   // u = wp1[0,:]-wp1[1,:]
            uv[10+tid] = wc1[tid] - wc1[10+tid];   // v = wc1[0,:]-wc1[1,:]
        }
        return;
    }
    int t = b*256 + tid;
    float sd = Sd[t], ed = Ed[t];
    float xv[8];
    #pragma unroll
    for(int k=0;k<8;k++) xv[k] = xf[t*8+k];
    #pragma unroll
    for(int j=0;j<10;j++){
        float a1 = bp1[j] - sd*wp1[j] + ed*wp1[10+j];
        float a2 = bc1[j] - sd*wc1[j] + ed*wc1[10+j];
        #pragma unroll
        for(int k=0;k<8;k++){
            a1 += xv[k]*wp1[(2+k)*10+j];
            a2 += xv[k]*wc1[(2+k)*10+j];
        }
        A[t*20+j]    = a1;
        A[t*20+10+j] = a2;
    }
}

// ---------------- kernel 4: HT[t][256] = H^T, zero-padded cols 192..255 ----------------
__global__ void k_transpose(const float* __restrict__ H, float* __restrict__ HT){
    __shared__ float tile[32][33];
    int bid = blockIdx.x;
    int tt = bid & 31, ht = bid >> 5;     // 32 t-tiles x 8 h-tiles
    int tx = threadIdx.x & 31, ty = threadIdx.x >> 5;
    #pragma unroll
    for(int k=0;k<4;k++){
        int h = ht*32 + ty + k*8, t = tt*32 + tx;
        tile[ty+k*8][tx] = (h < C) ? H[h*T + t] : 0.f;
    }
    __syncthreads();
    #pragma unroll
    for(int k=0;k<4;k++){
        int t = tt*32 + ty + k*8, h = ht*32 + tx;
        HT[t*256 + h] = tile[tx][ty+k*8];
    }
}

// ---------------- kernel 5: fold W_out into W_WH / W_WC / biases ----------------
__global__ void k_fold(const float* __restrict__ W_WH, const float* __restrict__ W_WC,
                       const float* __restrict__ b_WH, const float* __restrict__ b_WC,
                       const float* __restrict__ W_out, const float* __restrict__ b_out,
                       float* __restrict__ WWH2, float* __restrict__ WWC2, float* __restrict__ b2){
    int i = blockIdx.x, c = threadIdx.x;     // 192 threads
    if(i < 768){
        float a = 0.f;
        for(int j=0;j<C;j++) a += W_WH[i*C+j]*W_out[j*C+c];
        WWH2[i*C+c] = a;
    } else if(i < 776){
        int r = i-768;
        float a = 0.f;
        for(int j=0;j<C;j++) a += W_WC[r*C+j]*W_out[j*C+c];
        WWC2[r*C+c] = a;
    } else {
        float a = b_out[c];
        for(int j=0;j<C;j++) a += (b_WH[j]+b_WC[j])*W_out[j*C+c];
        b2[c] = a;
    }
}

// ---------------- kernel 6: main — 2 frames per block, 256 threads ----------------
__global__ void __launch_bounds__(256)
k_main(const float* __restrict__ HT, const float* __restrict__ A, const float* __restrict__ uv,
       const float* __restrict__ wp2, const float* __restrict__ bp2,
       const float* __restrict__ wc2, const float* __restrict__ bc2,
       const float* __restrict__ WWH2, const float* __restrict__ WWC2, const float* __restrict__ b2,
       float* __restrict__ out, int M)
{
    __shared__ __align__(16) float w_l[2][T][4];   // logits -> e; aliased as WH partials later
    __shared__ __align__(16) float WHf[2][768];
    __shared__ float wsm[96];   // wp2@0(40) bp2@40(4) wc2@44(20) bc2@64(2) u@66(10) v@76(10)
    __shared__ float scr[160];  // [w*8+..] max partials; [32 + w*24 + ..] sum/WC partials
    __shared__ float WCs[2][8];

    int tid = threadIdx.x;
    int w = tid >> 6, lane = tid & 63;
    int m0 = blockIdx.x*2;
    float fi[2] = {(float)(m0+1), (float)(m0+2)};

    if(tid < 40)      wsm[tid] = wp2[tid];
    else if(tid < 44) wsm[tid] = bp2[tid-40];
    else if(tid < 64) wsm[tid] = wc2[tid-44];
    else if(tid < 66) wsm[tid] = bc2[tid-64];
    else if(tid < 86) wsm[tid] = uv[tid-66];
    __syncthreads();

    // ---- phase 1: logits -> w_l, content -> regs, track max ----
    float pmax[2][4];
    #pragma unroll
    for(int mi=0;mi<2;mi++)
        #pragma unroll
        for(int q=0;q<4;q++) pmax[mi][q] = -3.0e38f;
    float cmr[2][4][2];

    #pragma unroll
    for(int ti=0; ti<4; ti++){
        int t = tid + ti*256;
        float Av[20];
        #pragma unroll
        for(int r=0;r<5;r++){
            float4 tmp = *(const float4*)(A + t*20 + r*4);
            Av[r*4+0]=tmp.x; Av[r*4+1]=tmp.y; Av[r*4+2]=tmp.z; Av[r*4+3]=tmp.w;
        }
        #pragma unroll
        for(int mi=0;mi<2;mi++){
            float h1[10], g1[10];
            #pragma unroll
            for(int j=0;j<10;j++) h1[j] = silu_f(Av[j]    + fi[mi]*wsm[66+j]);
            #pragma unroll
            for(int j=0;j<10;j++) g1[j] = silu_f(Av[10+j] + fi[mi]*wsm[76+j]);
            float l[4];
            #pragma unroll
            for(int q=0;q<4;q++){
                float a = wsm[40+q];
                #pragma unroll
                for(int j=0;j<10;j++) a += h1[j]*wsm[j*4+q];
                l[q] = a;
                pmax[mi][q] = fmaxf(pmax[mi][q], a);
            }
            *(float4*)&w_l[mi][t][0] = make_float4(l[0],l[1],l[2],l[3]);
            #pragma unroll
            for(int p=0;p<2;p++){
                float a = wsm[64+p];
                #pragma unroll
                for(int j=0;j<10;j++) a += g1[j]*wsm[44 + j*2 + p];
                cmr[mi][ti][p] = silu_f(a);
            }
        }
    }

    // ---- max reduce (wave shuffle + cross-wave LDS) ----
    #pragma unroll
    for(int mi=0;mi<2;mi++)
        #pragma unroll
        for(int q=0;q<4;q++) pmax[mi][q] = wred_max(pmax[mi][q]);
    if(lane==0){
        #pragma unroll
        for(int mi=0;mi<2;mi++)
            #pragma unroll
            for(int q=0;q<4;q++) scr[w*8 + mi*4 + q] = pmax[mi][q];
    }
    __syncthreads();
    float mx[2][4];
    #pragma unroll
    for(int mi=0;mi<2;mi++)
        #pragma unroll
        for(int q=0;q<4;q++){
            float a = scr[0*8+mi*4+q];
            a = fmaxf(a, scr[1*8+mi*4+q]);
            a = fmaxf(a, scr[2*8+mi*4+q]);
            a = fmaxf(a, scr[3*8+mi*4+q]);
            mx[mi][q] = a;
        }

    // ---- exp sweep: e -> w_l, accumulate sum + WC partials ----
    float sp[2][4];
    float wcp[2][4][2];
    #pragma unroll
    for(int mi=0;mi<2;mi++)
        #pragma unroll
        for(int q=0;q<4;q++){ sp[mi][q]=0.f; wcp[mi][q][0]=0.f; wcp[mi][q][1]=0.f; }

    #pragma unroll
    for(int ti=0; ti<4; ti++){
        int t = tid + ti*256;
        #pragma unroll
        for(int mi=0;mi<2;mi++){
            float4 lv = *(const float4*)&w_l[mi][t][0];
            float e0 = __expf(lv.x - mx[mi][0]);
            float e1 = __expf(lv.y - mx[mi][1]);
            float e2 = __expf(lv.z - mx[mi][2]);
            float e3 = __expf(lv.w - mx[mi][3]);
            *(float4*)&w_l[mi][t][0] = make_float4(e0,e1,e2,e3);
            sp[mi][0]+=e0; sp[mi][1]+=e1; sp[mi][2]+=e2; sp[mi][3]+=e3;
            float c0 = cmr[mi][ti][0], c1 = cmr[mi][ti][1];
            wcp[mi][0][0]+=e0*c0; wcp[mi][0][1]+=e0*c1;
            wcp[mi][1][0]+=e1*c0; wcp[mi][1][1]+=e1*c1;
            wcp[mi][2][0]+=e2*c0; wcp[mi][2][1]+=e2*c1;
            wcp[mi][3][0]+=e3*c0; wcp[mi][3][1]+=e3*c1;
        }
    }
    #pragma unroll
    for(int mi=0;mi<2;mi++)
        #pragma unroll
        for(int q=0;q<4;q++){
            sp[mi][q] = wred_sum(sp[mi][q]);
            wcp[mi][q][0] = wred_sum(wcp[mi][q][0]);
            wcp[mi][q][1] = wred_sum(wcp[mi][q][1]);
        }
    if(lane==0){
        int base = 32 + w*24;
        #pragma unroll
        for(int mi=0;mi<2;mi++)
            #pragma unroll
            for(int q=0;q<4;q++){
                scr[base + mi*4 + q] = sp[mi][q];
                scr[base + 8 + (mi*4+q)*2 + 0] = wcp[mi][q][0];
                scr[base + 8 + (mi*4+q)*2 + 1] = wcp[mi][q][1];
            }
    }
    __syncthreads();   // publishes e-values in w_l AND the partials

    float inv[2][4];
    #pragma unroll
    for(int mi=0;mi<2;mi++)
        #pragma unroll
        for(int q=0;q<4;q++){
            float s = scr[32+0*24+mi*4+q] + scr[32+1*24+mi*4+q]
                    + scr[32+2*24+mi*4+q] + scr[32+3*24+mi*4+q];
            inv[mi][q] = 1.0f/s;
        }
    if(tid < 16){
        int mi = tid>>3, q = (tid>>1)&3, p = tid&1;
        float s2 = scr[32+0*24+8+(mi*4+q)*2+p] + scr[32+1*24+8+(mi*4+q)*2+p]
                 + scr[32+2*24+8+(mi*4+q)*2+p] + scr[32+3*24+8+(mi*4+q)*2+p];
        WCs[mi][q*2+p] = s2 * inv[mi][q];
    }

    // ---- pass 2: WH accumulation, register tile 4h x 4q x 2m, no barriers ----
    float4 acc[2][4];
    #pragma unroll
    for(int mi=0;mi<2;mi++)
        #pragma unroll
        for(int q=0;q<4;q++) acc[mi][q] = make_float4(0.f,0.f,0.f,0.f);

    int lane4 = lane*4;
    #define FMA4(av, s, hv) { av.x += (s)*(hv).x; av.y += (s)*(hv).y; av.z += (s)*(hv).z; av.w += (s)*(hv).w; }
    for(int t = w; t < T; t += 8){
        int t2 = t + 4;
        float4 hv0 = *(const float4*)(HT + (size_t)t *256 + lane4);
        float4 hv1 = *(const float4*)(HT + (size_t)t2*256 + lane4);
        float4 ea0 = *(const float4*)&w_l[0][t ][0];
        float4 eb0 = *(const float4*)&w_l[1][t ][0];
        float4 ea1 = *(const float4*)&w_l[0][t2][0];
        float4 eb1 = *(const float4*)&w_l[1][t2][0];
        FMA4(acc[0][0], ea0.x, hv0); FMA4(acc[0][1], ea0.y, hv0);
        FMA4(acc[0][2], ea0.z, hv0); FMA4(acc[0][3], ea0.w, hv0);
        FMA4(acc[1][0], eb0.x, hv0); FMA4(acc[1][1], eb0.y, hv0);
        FMA4(acc[1][2], eb0.z, hv0); FMA4(acc[1][3], eb0.w, hv0);
        FMA4(acc[0][0], ea1.x, hv1); FMA4(acc[0][1], ea1.y, hv1);
        FMA4(acc[0][2], ea1.z, hv1); FMA4(acc[0][3], ea1.w, hv1);
        FMA4(acc[1][0], eb1.x, hv1); FMA4(acc[1][1], eb1.y, hv1);
        FMA4(acc[1][2], eb1.z, hv1); FMA4(acc[1][3], eb1.w, hv1);
    }
    #undef FMA4

    __syncthreads();                       // everyone done reading w_l
    float* part = &w_l[0][0][0];           // alias: [w][mi][q][lane] float4 = 8192 floats
    #pragma unroll
    for(int mi=0;mi<2;mi++)
        #pragma unroll
        for(int q=0;q<4;q++){
            int idx = (((w*2+mi)*4 + q)*64 + lane)*4;
            *(float4*)(part + idx) = acc[mi][q];
        }
    __syncthreads();
    #pragma unroll
    for(int rr=0; rr<2; rr++){
        int task = tid + rr*256;           // 512 tasks: (mi, q, l)
        int mi = task >> 8, q = (task >> 6) & 3, l = task & 63;
        float4 s = make_float4(0.f,0.f,0.f,0.f);
        #pragma unroll
        for(int w4=0; w4<4; w4++){
            float4 p4 = *(const float4*)(part + (((w4*2+mi)*4 + q)*64 + l)*4);
            s.x += p4.x; s.y += p4.y; s.z += p4.z; s.w += p4.w;
        }
        int h0 = l*4;
        if(h0 < C){
            float sc = inv[mi][q];
            WHf[mi][q*C + h0 + 0] = s.x*sc;
            WHf[mi][q*C + h0 + 1] = s.y*sc;
            WHf[mi][q*C + h0 + 2] = s.z*sc;
            WHf[mi][q*C + h0 + 3] = s.w*sc;
        }
    }
    __syncthreads();

    // ---- epilogue: O[m] = WHf@WWH2 + WCs@WWC2 + b2 ----
    if(tid < C){
        float o0 = b2[tid], o1 = o0;
        for(int i=0; i<768; i+=4){
            float4 wh0 = *(const float4*)&WHf[0][i];
            float4 wh1 = *(const float4*)&WHf[1][i];
            float cw0 = WWH2[(i+0)*C + tid];
            float cw1 = WWH2[(i+1)*C + tid];
            float cw2 = WWH2[(i+2)*C + tid];
            float cw3 = WWH2[(i+3)*C + tid];
            o0 += wh0.x*cw0 + wh0.y*cw1 + wh0.z*cw2 + wh0.w*cw3;
            o1 += wh1.x*cw0 + wh1.y*cw1 + wh1.z*cw2 + wh1.w*cw3;
        }
        #pragma unroll
        for(int i=0;i<8;i++){
            float cw = WWC2[i*C + tid];
            o0 += WCs[0][i]*cw;
            o1 += WCs[1][i]*cw;
        }
        out[(size_t)tid*M + m0] = o0;
        if(m0+1 < M) out[(size_t)tid*M + m0 + 1] = o1;
    } else if(tid == C){
        out[(size_t)C*M + m0] = 0.f;
    } else if(tid == C+1){
        if(m0+1 < M) out[(size_t)C*M + m0 + 1] = 0.f;
    }
}

// ---------------- host ----------------
extern "C" void kernel_launch(void* const* d_in, const int* in_sizes, int n_in,
                              void* d_out, int out_size, void* d_ws, size_t ws_size,
                              hipStream_t stream)
{
    const float* H      = (const float*)d_in[0];
    const int*   d      = (const int*)  d_in[1];
    const float* W_in   = (const float*)d_in[3];
    const float* b_in   = (const float*)d_in[4];
    const float* conv_w = (const float*)d_in[5];
    const float* conv_b = (const float*)d_in[6];
    const float* gamma  = (const float*)d_in[7];
    const float* beta   = (const float*)d_in[8];
    const float* wp1    = (const float*)d_in[9];
    const float* bp1    = (const float*)d_in[10];
    const float* wp2    = (const float*)d_in[11];
    const float* bp2    = (const float*)d_in[12];
    const float* wc1    = (const float*)d_in[13];
    const float* bc1    = (const float*)d_in[14];
    const float* wc2    = (const float*)d_in[15];
    const float* bc2    = (const float*)d_in[16];
    const float* W_WH   = (const float*)d_in[17];
    const float* b_WH   = (const float*)d_in[18];
    const float* W_WC   = (const float*)d_in[19];
    const float* b_WC   = (const float*)d_in[20];
    const float* W_out  = (const float*)d_in[21];
    const float* b_out  = (const float*)d_in[22];

    float* out = (float*)d_out;
    int M = out_size / 193;          // out = [192*M] O + [M] ~frame_valid

    float* ws   = (float*)d_ws;
    float* Sd   = ws;                 // 1024
    float* Ed   = ws + 1024;          // 1024
    float* A    = ws + 2048;          // 1024*20 = 20480
    float* uvp  = ws + 22528;         // 20 (pad to 32)
    float* WWH2 = ws + 22560;         // 768*192 = 147456
    float* WWC2 = ws + 170016;        // 8*192 = 1536
    float* b2   = ws + 171552;        // 192 (pad to 224)
    float* HT   = ws + 171776;        // 1024*256 = 262144
    float* x    = ws + 171776;        // alias HT (x dead before transpose runs)
    float* xf   = ws + 433920;        // 1024*8 = 8192   (end = 442112 floats = 1.73 MB)

    hipLaunchKernelGGL(k_scan,      dim3(1),    dim3(1024), 0, stream, d, Sd, Ed);
    hipLaunchKernelGGL(k_proj_in,   dim3(T),    dim3(C),    0, stream, H, W_in, b_in, x);
    hipLaunchKernelGGL(k_conv_ln,   dim3(T/32), dim3(256),  0, stream, x, conv_w, conv_b, gamma, beta, xf);
    hipLaunchKernelGGL(k_A,         dim3(5),    dim3(256),  0, stream, Sd, Ed, xf, wp1, bp1, wc1, bc1, A, uvp);
    hipLaunchKernelGGL(k_transpose, dim3(256),  dim3(256),  0, stream, H, HT);
    hipLaunchKernelGGL(k_fold,      dim3(777),  dim3(C),    0, stream, W_WH, W_WC, b_WH, b_WC, W_out, b_out, WWH2, WWC2, b2);
    hipLaunchKernelGGL(k_main,      dim3((M+1)/2), dim3(256), 0, stream,
                       HT, A, uvp, wp2, bp2, wc2, bc2, WWH2, WWC2, b2, out, M);
}

// Round 3
// 354.552 us; speedup vs baseline: 4.1104x; 1.6019x over previous
//
#include <hip/hip_runtime.h>
#include <hip/hip_bf16.h>
#include <math.h>

#define T 1024
#define C 192
#define LN_EPS 1e-5f

__device__ __forceinline__ float silu_f(float x){ return x / (1.0f + __expf(-x)); }
__device__ __forceinline__ float wred_max(float v){
    #pragma unroll
    for(int o=32;o;o>>=1) v = fmaxf(v, __shfl_xor(v,o));
    return v;
}
__device__ __forceinline__ float wred_sum(float v){
    #pragma unroll
    for(int o=32;o;o>>=1) v += __shfl_xor(v,o);
    return v;
}

// ---------------- kernel 0: inclusive scan of durations ----------------
__global__ void k_scan(const int* __restrict__ d, float* __restrict__ Sd, float* __restrict__ Ed){
    __shared__ int s[T];
    int tid = threadIdx.x;
    int v = d[tid];
    s[tid] = v;
    for(int off=1; off<T; off<<=1){
        __syncthreads();
        int add = (tid>=off) ? s[tid-off] : 0;
        __syncthreads();
        s[tid] += add;
    }
    __syncthreads();
    Ed[tid] = (float)s[tid];
    Sd[tid] = (float)(s[tid]-v);
}

// ---------------- kernel 1: x = silu(H^T W_in + b_in) [T][C], 16 t per block ----------------
__global__ void k_proj_in(const float* __restrict__ H, const float* __restrict__ W_in,
                          const float* __restrict__ b_in, float* __restrict__ x){
    __shared__ float Hs[192*16];
    int tid = threadIdx.x;          // 192 threads
    int t0 = blockIdx.x*16;
    for(int idx=tid; idx<192*16; idx+=192){
        int ci = idx>>4, j = idx&15;
        Hs[idx] = H[ci*T + t0 + j];
    }
    __syncthreads();
    int c = tid;
    float acc[16];
    float bb = b_in[c];
    #pragma unroll
    for(int j=0;j<16;j++) acc[j] = bb;
    for(int ci=0; ci<192; ci++){
        float wv = W_in[ci*C + c];
        #pragma unroll
        for(int j4=0;j4<4;j4++){
            float4 h4 = *(const float4*)&Hs[ci*16 + j4*4];
            acc[j4*4+0] += h4.x*wv;
            acc[j4*4+1] += h4.y*wv;
            acc[j4*4+2] += h4.z*wv;
            acc[j4*4+3] += h4.w*wv;
        }
    }
    #pragma unroll
    for(int j=0;j<16;j++) x[(t0+j)*C + c] = silu_f(acc[j]);
}

// ---------------- kernel 2: conv1d(C->8,k3,p1) + LN(8) + SiLU -> xf [T][8] ----------------
__global__ void k_conv_ln(const float* __restrict__ x, const float* __restrict__ conv_w,
                          const float* __restrict__ conv_b, const float* __restrict__ gamma,
                          const float* __restrict__ beta, float* __restrict__ xf){
    __shared__ float xc[32][8];
    int tid = threadIdx.x;          // 256 = 32 t x 8 f
    int tl = tid >> 3, f = tid & 7;
    int t = blockIdx.x*32 + tl;
    float acc = conv_b[f];
    for(int k=0;k<3;k++){
        int tt = t + k - 1;
        if(tt>=0 && tt<T){
            const float* xr = x + tt*C;
            const float* wr = conv_w + f*C*3 + k;   // conv_w[f][c][k]
            for(int c2=0;c2<C;c2++) acc += xr[c2]*wr[c2*3];
        }
    }
    xc[tl][f] = acc;
    __syncthreads();
    float mu=0.f;
    #pragma unroll
    for(int j=0;j<8;j++) mu += xc[tl][j];
    mu *= 0.125f;
    float var=0.f;
    #pragma unroll
    for(int j=0;j<8;j++){ float dd = xc[tl][j]-mu; var += dd*dd; }
    var *= 0.125f;
    float vi = rsqrtf(var + LN_EPS);
    float v = (acc - mu)*vi*gamma[f] + beta[f];
    xf[t*8+f] = silu_f(v);
}

// ---------------- kernel 3: A1/A2 [t][12] = m-independent first-layer preacts; uv ----------------
__global__ void k_A(const float* __restrict__ Sd, const float* __restrict__ Ed,
                    const float* __restrict__ xf,
                    const float* __restrict__ wp1, const float* __restrict__ bp1,
                    const float* __restrict__ wc1, const float* __restrict__ bc1,
                    float* __restrict__ A1, float* __restrict__ A2, float* __restrict__ uv){
    int b = blockIdx.x, tid = threadIdx.x;
    if(b==4){
        if(tid<10){
            uv[tid]    = wp1[tid] - wp1[10+tid];   // u = wp1[0,:]-wp1[1,:]
            uv[10+tid] = wc1[tid] - wc1[10+tid];   // v = wc1[0,:]-wc1[1,:]
        }
        return;
    }
    int t = b*256 + tid;
    float sd = Sd[t], ed = Ed[t];
    float xv[8];
    #pragma unroll
    for(int k=0;k<8;k++) xv[k] = xf[t*8+k];
    #pragma unroll
    for(int j=0;j<10;j++){
        float a1 = bp1[j] - sd*wp1[j] + ed*wp1[10+j];
        float a2 = bc1[j] - sd*wc1[j] + ed*wc1[10+j];
        #pragma unroll
        for(int k=0;k<8;k++){
            a1 += xv[k]*wp1[(2+k)*10+j];
            a2 += xv[k]*wc1[(2+k)*10+j];
        }
        A1[t*12+j] = a1;
        A2[t*12+j] = a2;
    }
    A1[t*12+10]=0.f; A1[t*12+11]=0.f;
    A2[t*12+10]=0.f; A2[t*12+11]=0.f;
}

// ---------------- kernel 4: HT[t][192] = H^T ----------------
__global__ void k_transpose(const float* __restrict__ H, float* __restrict__ HT){
    __shared__ float tile[32][33];
    int bid = blockIdx.x;
    int tt = bid & 31, ht = bid >> 5;     // 32 t-tiles x 6 h-tiles
    int tx = threadIdx.x & 31, ty = threadIdx.x >> 5;
    #pragma unroll
    for(int k=0;k<4;k++){
        int h = ht*32 + ty + k*8, t = tt*32 + tx;
        tile[ty+k*8][tx] = H[h*T + t];
    }
    __syncthreads();
    #pragma unroll
    for(int k=0;k<4;k++){
        int t = tt*32 + ty + k*8, h = ht*32 + tx;
        HT[t*C + h] = tile[tx][ty+k*8];
    }
}

// ---------------- kernel 5: fold W_out into W_WH (bf16 pairs) / W_WC / bias ----------------
__global__ void k_fold(const float* __restrict__ W_WH, const float* __restrict__ W_WC,
                       const float* __restrict__ b_WH, const float* __restrict__ b_WC,
                       const float* __restrict__ W_out, const float* __restrict__ b_out,
                       __hip_bfloat16* __restrict__ Wcat2, float* __restrict__ WWC2,
                       float* __restrict__ b2){
    int i = blockIdx.x, c = threadIdx.x;     // 192 threads
    if(i < 768){
        float a = 0.f;
        for(int j=0;j<C;j++) a += W_WH[i*C+j]*W_out[j*C+c];
        // pair layout: row = i>>1, slot = c*2 + (i&1)  -> uint read gives (i0,i1) for column c
        Wcat2[(i>>1)*384 + c*2 + (i&1)] = __float2bfloat16(a);
    } else if(i < 776){
        int r = i-768;
        float a = 0.f;
        for(int j=0;j<C;j++) a += W_WC[r*C+j]*W_out[j*C+c];
        WWC2[r*C+c] = a;
    } else {
        float a = b_out[c];
        for(int j=0;j<C;j++) a += (b_WH[j]+b_WC[j])*W_out[j*C+c];
        b2[c] = a;
    }
}

// ---------------- kernel 6: main — 2 frames/block, 256 threads, 4 blocks/CU ----------------
__global__ void __launch_bounds__(256, 4)
k_main(const float* __restrict__ HT, const float* __restrict__ A1, const float* __restrict__ A2,
       const float* __restrict__ uv,
       const float* __restrict__ wp2, const float* __restrict__ bp2,
       const float* __restrict__ wc2, const float* __restrict__ bc2,
       const __hip_bfloat16* __restrict__ Wcat2, const float* __restrict__ WWC2,
       const float* __restrict__ b2,
       float* __restrict__ out, int M)
{
    __shared__ __align__(16) float w_l[2][T][4];   // logits -> e; aliased as WH partials later
    __shared__ __align__(16) float WHf[2][768];
    __shared__ float wsm[96];   // wp2@0(40) bp2@40(4) wc2@44(20) bc2@64(2) u@66(10) v@76(10)
    __shared__ float scr[160];  // 0..31 max | 32..127 sum/wc partials | 128..143 WCs | 144..151 inv

    int tid = threadIdx.x;
    int w = tid >> 6, lane = tid & 63;
    int m0 = blockIdx.x*2;
    float fis[2] = {(float)(m0+1), (float)(m0+2)};

    if(tid < 40)      wsm[tid] = wp2[tid];
    else if(tid < 44) wsm[tid] = bp2[tid-40];
    else if(tid < 64) wsm[tid] = wc2[tid-44];
    else if(tid < 66) wsm[tid] = bc2[tid-64];
    else if(tid < 86) wsm[tid] = uv[tid-66];
    __syncthreads();

    // ---- phase 1: W-path MLP -> logits in w_l, track max ----
    float pmax[2][4];
    #pragma unroll
    for(int mi=0;mi<2;mi++){
        #pragma unroll
        for(int q=0;q<4;q++) pmax[mi][q] = -3.0e38f;
    }
    for(int ti=0; ti<4; ti++){
        int t = tid + ti*256;
        float4 a0 = *(const float4*)(A1 + t*12);
        float4 a1 = *(const float4*)(A1 + t*12 + 4);
        float4 a2 = *(const float4*)(A1 + t*12 + 8);
        float Av[10] = {a0.x,a0.y,a0.z,a0.w,a1.x,a1.y,a1.z,a1.w,a2.x,a2.y};
        #pragma unroll
        for(int mi=0;mi<2;mi++){
            float fi = fis[mi];
            float h1[10];
            #pragma unroll
            for(int j=0;j<10;j++) h1[j] = silu_f(Av[j] + fi*wsm[66+j]);
            float l0=wsm[40], l1=wsm[41], l2=wsm[42], l3=wsm[43];
            #pragma unroll
            for(int j=0;j<10;j++){
                float h = h1[j];
                l0 += h*wsm[j*4+0]; l1 += h*wsm[j*4+1];
                l2 += h*wsm[j*4+2]; l3 += h*wsm[j*4+3];
            }
            *(float4*)&w_l[mi][t][0] = make_float4(l0,l1,l2,l3);
            pmax[mi][0]=fmaxf(pmax[mi][0],l0); pmax[mi][1]=fmaxf(pmax[mi][1],l1);
            pmax[mi][2]=fmaxf(pmax[mi][2],l2); pmax[mi][3]=fmaxf(pmax[mi][3],l3);
        }
    }

    // ---- max reduce ----
    #pragma unroll
    for(int mi=0;mi<2;mi++){
        #pragma unroll
        for(int q=0;q<4;q++) pmax[mi][q] = wred_max(pmax[mi][q]);
    }
    if(lane==0){
        #pragma unroll
        for(int mi=0;mi<2;mi++){
            #pragma unroll
            for(int q=0;q<4;q++) scr[w*8 + mi*4 + q] = pmax[mi][q];
        }
    }
    __syncthreads();
    float mx[2][4];
    #pragma unroll
    for(int mi=0;mi<2;mi++){
        #pragma unroll
        for(int q=0;q<4;q++){
            float a = fmaxf(scr[0*8+mi*4+q], scr[1*8+mi*4+q]);
            float bq = fmaxf(scr[2*8+mi*4+q], scr[3*8+mi*4+q]);
            mx[mi][q] = fmaxf(a,bq);
        }
    }

    // ---- sweep: C-path MLP + exp (e -> w_l) + sums + WC partials ----
    float sp[2][4], wcp[2][4][2];
    #pragma unroll
    for(int mi=0;mi<2;mi++){
        #pragma unroll
        for(int q=0;q<4;q++){ sp[mi][q]=0.f; wcp[mi][q][0]=0.f; wcp[mi][q][1]=0.f; }
    }
    for(int ti=0; ti<4; ti++){
        int t = tid + ti*256;
        float4 a0 = *(const float4*)(A2 + t*12);
        float4 a1 = *(const float4*)(A2 + t*12 + 4);
        float4 a2 = *(const float4*)(A2 + t*12 + 8);
        float Av[10] = {a0.x,a0.y,a0.z,a0.w,a1.x,a1.y,a1.z,a1.w,a2.x,a2.y};
        #pragma unroll
        for(int mi=0;mi<2;mi++){
            float fi = fis[mi];
            float g1[10];
            #pragma unroll
            for(int j=0;j<10;j++) g1[j] = silu_f(Av[j] + fi*wsm[76+j]);
            float c0 = wsm[64], c1 = wsm[65];
            #pragma unroll
            for(int j=0;j<10;j++){
                c0 += g1[j]*wsm[44 + j*2 + 0];
                c1 += g1[j]*wsm[44 + j*2 + 1];
            }
            c0 = silu_f(c0); c1 = silu_f(c1);
            float4 lv = *(const float4*)&w_l[mi][t][0];
            float e0 = __expf(lv.x - mx[mi][0]);
            float e1 = __expf(lv.y - mx[mi][1]);
            float e2 = __expf(lv.z - mx[mi][2]);
            float e3 = __expf(lv.w - mx[mi][3]);
            *(float4*)&w_l[mi][t][0] = make_float4(e0,e1,e2,e3);
            sp[mi][0]+=e0; sp[mi][1]+=e1; sp[mi][2]+=e2; sp[mi][3]+=e3;
            wcp[mi][0][0]+=e0*c0; wcp[mi][0][1]+=e0*c1;
            wcp[mi][1][0]+=e1*c0; wcp[mi][1][1]+=e1*c1;
            wcp[mi][2][0]+=e2*c0; wcp[mi][2][1]+=e2*c1;
            wcp[mi][3][0]+=e3*c0; wcp[mi][3][1]+=e3*c1;
        }
    }
    #pragma unroll
    for(int mi=0;mi<2;mi++){
        #pragma unroll
        for(int q=0;q<4;q++){
            sp[mi][q] = wred_sum(sp[mi][q]);
            wcp[mi][q][0] = wred_sum(wcp[mi][q][0]);
            wcp[mi][q][1] = wred_sum(wcp[mi][q][1]);
        }
    }
    if(lane==0){
        int base = 32 + w*24;
        #pragma unroll
        for(int mi=0;mi<2;mi++){
            #pragma unroll
            for(int q=0;q<4;q++){
                scr[base + mi*4 + q] = sp[mi][q];
                scr[base + 8 + (mi*4+q)*2 + 0] = wcp[mi][q][0];
                scr[base + 8 + (mi*4+q)*2 + 1] = wcp[mi][q][1];
            }
        }
    }
    __syncthreads();   // publishes e-values in w_l AND the partials

    if(tid < 8){   // inv[mi*4+q] -> scr[144+tid]
        float s = scr[32+0*24+tid] + scr[32+1*24+tid] + scr[32+2*24+tid] + scr[32+3*24+tid];
        scr[144+tid] = 1.0f/s;
    }
    if(tid < 16){  // WCs (normalized) -> scr[128+tid]
        int mq = tid >> 1;
        float s2 = scr[32+0*24+8+tid] + scr[32+1*24+8+tid]
                 + scr[32+2*24+8+tid] + scr[32+3*24+8+tid];
        float den = scr[32+0*24+mq] + scr[32+1*24+mq] + scr[32+2*24+mq] + scr[32+3*24+mq];
        scr[128+tid] = s2/den;
    }

    // ---- pass 2: WH accumulation; wave w handles t in {2w,2w+1} mod 8 ----
    float acc[2][4][3];
    #pragma unroll
    for(int mi=0;mi<2;mi++){
        #pragma unroll
        for(int q=0;q<4;q++){ acc[mi][q][0]=0.f; acc[mi][q][1]=0.f; acc[mi][q][2]=0.f; }
    }
    #define ACC3(A, s, h0, h1, h2) { (A)[0]+=(s)*(h0); (A)[1]+=(s)*(h1); (A)[2]+=(s)*(h2); }
    #pragma unroll 2
    for(int t0 = 2*w; t0 < T; t0 += 8){
        const float* hp = HT + t0*C + lane;
        float ha0 = hp[0],   ha1 = hp[64],  ha2 = hp[128];
        float hb0 = hp[192], hb1 = hp[256], hb2 = hp[320];
        float4 ea = *(const float4*)&w_l[0][t0][0];
        float4 eb = *(const float4*)&w_l[1][t0][0];
        float4 fa = *(const float4*)&w_l[0][t0+1][0];
        float4 fb = *(const float4*)&w_l[1][t0+1][0];
        ACC3(acc[0][0], ea.x, ha0,ha1,ha2); ACC3(acc[0][1], ea.y, ha0,ha1,ha2);
        ACC3(acc[0][2], ea.z, ha0,ha1,ha2); ACC3(acc[0][3], ea.w, ha0,ha1,ha2);
        ACC3(acc[1][0], eb.x, ha0,ha1,ha2); ACC3(acc[1][1], eb.y, ha0,ha1,ha2);
        ACC3(acc[1][2], eb.z, ha0,ha1,ha2); ACC3(acc[1][3], eb.w, ha0,ha1,ha2);
        ACC3(acc[0][0], fa.x, hb0,hb1,hb2); ACC3(acc[0][1], fa.y, hb0,hb1,hb2);
        ACC3(acc[0][2], fa.z, hb0,hb1,hb2); ACC3(acc[0][3], fa.w, hb0,hb1,hb2);
        ACC3(acc[1][0], fb.x, hb0,hb1,hb2); ACC3(acc[1][1], fb.y, hb0,hb1,hb2);
        ACC3(acc[1][2], fb.z, hb0,hb1,hb2); ACC3(acc[1][3], fb.w, hb0,hb1,hb2);
    }
    #undef ACC3

    __syncthreads();                       // everyone done reading w_l
    float* part = &w_l[0][0][0];           // alias: [(w*8 + mi*4 + q)*192 + h], 6144 floats
    #pragma unroll
    for(int mi=0;mi<2;mi++){
        #pragma unroll
        for(int q=0;q<4;q++){
            #pragma unroll
            for(int hh=0;hh<3;hh++)
                part[(w*8 + mi*4 + q)*192 + hh*64 + lane] = acc[mi][q][hh];
        }
    }
    __syncthreads();
    #pragma unroll
    for(int r=0;r<6;r++){
        int idx = tid + r*256;             // 1536 tasks: (mi, q, h)
        int mi = (idx >= 768) ? 1 : 0;
        int rem = idx - mi*768;
        int q = rem/192;
        int h = rem - q*192;
        float s = part[(0*8+mi*4+q)*192+h] + part[(1*8+mi*4+q)*192+h]
                + part[(2*8+mi*4+q)*192+h] + part[(3*8+mi*4+q)*192+h];
        WHf[mi][rem] = s * scr[144 + mi*4 + q];
    }
    __syncthreads();

    // ---- epilogue: O[m] = WHf@Wcat(bf16) + WCs@WWC2 + b2 ----
    if(tid < C){
        int c = tid;
        float o0 = b2[c], o1 = o0;
        const unsigned int* wp = (const unsigned int*)Wcat2;
        for(int pr=0; pr<384; pr++){
            unsigned int u = wp[pr*192 + c];
            float w0 = __uint_as_float(u << 16);
            float w1 = __uint_as_float(u & 0xffff0000u);
            float2 p0 = *(const float2*)&WHf[0][pr*2];
            float2 p1 = *(const float2*)&WHf[1][pr*2];
            o0 += p0.x*w0 + p0.y*w1;
            o1 += p1.x*w0 + p1.y*w1;
        }
        #pragma unroll
        for(int i=0;i<8;i++){
            float wv = WWC2[i*C + c];
            o0 += scr[128+i]*wv;
            o1 += scr[136+i]*wv;
        }
        out[(size_t)c*M + m0] = o0;
        if(m0+1 < M) out[(size_t)c*M + m0 + 1] = o1;
    } else if(tid == C){
        out[(size_t)C*M + m0] = 0.f;
        if(m0+1 < M) out[(size_t)C*M + m0 + 1] = 0.f;
    }
}

// ---------------- host ----------------
extern "C" void kernel_launch(void* const* d_in, const int* in_sizes, int n_in,
                              void* d_out, int out_size, void* d_ws, size_t ws_size,
                              hipStream_t stream)
{
    const float* H      = (const float*)d_in[0];
    const int*   d      = (const int*)  d_in[1];
    const float* W_in   = (const float*)d_in[3];
    const float* b_in   = (const float*)d_in[4];
    const float* conv_w = (const float*)d_in[5];
    const float* conv_b = (const float*)d_in[6];
    const float* gamma  = (const float*)d_in[7];
    const float* beta   = (const float*)d_in[8];
    const float* wp1    = (const float*)d_in[9];
    const float* bp1    = (const float*)d_in[10];
    const float* wp2    = (const float*)d_in[11];
    const float* bp2    = (const float*)d_in[12];
    const float* wc1    = (const float*)d_in[13];
    const float* bc1    = (const float*)d_in[14];
    const float* wc2    = (const float*)d_in[15];
    const float* bc2    = (const float*)d_in[16];
    const float* W_WH   = (const float*)d_in[17];
    const float* b_WH   = (const float*)d_in[18];
    const float* W_WC   = (const float*)d_in[19];
    const float* b_WC   = (const float*)d_in[20];
    const float* W_out  = (const float*)d_in[21];
    const float* b_out  = (const float*)d_in[22];

    float* out = (float*)d_out;
    int M = out_size / 193;          // out = [192*M] O + [M] ~frame_valid

    // ws layout (float offsets); x aliases HT (x dead before k_transpose runs)
    float* ws   = (float*)d_ws;
    float* Sd   = ws;                         // 1024
    float* Ed   = ws + 1024;                  // 1024
    float* A1   = ws + 2048;                  // 1024*12
    float* A2   = ws + 14336;                 // 1024*12
    float* uvp  = ws + 26624;                 // 20 (pad 32)
    float* WWC2 = ws + 26656;                 // 8*192
    float* b2   = ws + 28192;                 // 192
    float* HT   = ws + 28384;                 // 1024*192 (alias x)
    float* x    = ws + 28384;
    float* xf   = ws + 224992;                // 1024*8
    __hip_bfloat16* Wcat2 = (__hip_bfloat16*)(ws + 233184);  // 384*384 ushorts
    // end: 233184 + 73728 floats = 306912 floats ~= 1.23 MB

    hipLaunchKernelGGL(k_scan,      dim3(1),   dim3(1024), 0, stream, d, Sd, Ed);
    hipLaunchKernelGGL(k_proj_in,   dim3(64),  dim3(192),  0, stream, H, W_in, b_in, x);
    hipLaunchKernelGGL(k_conv_ln,   dim3(32),  dim3(256),  0, stream, x, conv_w, conv_b, gamma, beta, xf);
    hipLaunchKernelGGL(k_A,         dim3(5),   dim3(256),  0, stream, Sd, Ed, xf, wp1, bp1, wc1, bc1, A1, A2, uvp);
    hipLaunchKernelGGL(k_transpose, dim3(192), dim3(256),  0, stream, H, HT);
    hipLaunchKernelGGL(k_fold,      dim3(777), dim3(192),  0, stream, W_WH, W_WC, b_WH, b_WC, W_out, b_out, Wcat2, WWC2, b2);
    hipLaunchKernelGGL(k_main,      dim3((M+1)/2), dim3(256), 0, stream,
                       HT, A1, A2, uvp, wp2, bp2, wc2, bc2, Wcat2, WWC2, b2, out, M);
}